// Round 5
// baseline (395.922 us; speedup 1.0000x reference)
//
#include <hip/hip_runtime.h>
#include <hip/hip_cooperative_groups.h>
#include <math.h>

namespace cg = cooperative_groups;

#define NB 32
#define LQ 2048
#define LK 2048
#define HD 1024
#define AD 512
#define QCH 32   // q-chunks for first-stage query reduction (1024 tasks)

// ---------------- Phase 1: partial[qc][b][h] = sum over 64-row q-chunk ----------------
__device__ __forceinline__ void phase1(int G, int bid, int t,
        const float* __restrict__ query, float* __restrict__ partial) {
    for (int task = bid; task < NB * QCH; task += G) {
        int b = task / QCH, qc = task % QCH;
        const int QPC = LQ / QCH;        // 64 rows
        float4 a0 = {0.f, 0.f, 0.f, 0.f};
        float4 a1 = {0.f, 0.f, 0.f, 0.f};
        const float4* src = (const float4*)(query + ((size_t)b * LQ + (size_t)qc * QPC) * HD);
        for (int q = 0; q < QPC; q += 2) {
            float4 v0 = src[(size_t)q * (HD / 4) + t];
            float4 v1 = src[(size_t)(q + 1) * (HD / 4) + t];
            a0.x += v0.x; a0.y += v0.y; a0.z += v0.z; a0.w += v0.w;
            a1.x += v1.x; a1.y += v1.y; a1.z += v1.z; a1.w += v1.w;
        }
        float4 acc = {a0.x + a1.x, a0.y + a1.y, a0.z + a1.z, a0.w + a1.w};
        ((float4*)(partial + ((size_t)qc * NB + b) * HD))[t] = acc;
    }
}

// ---------------- Phase 2: 513 tasks: qsum (0..255) | wv_eff (256..511) | c_v (512) ----------------
__device__ __forceinline__ void phase2(int G, int bid, int t,
        const float* __restrict__ partial, const float* __restrict__ Wq,
        const float* __restrict__ bq, const float* __restrict__ Wk,
        const float* __restrict__ Wv, const float* __restrict__ bk,
        const float* __restrict__ bv, float* __restrict__ qsum,
        float* __restrict__ wv_eff, float* __restrict__ c_v) {
    __shared__ float sq[HD];
    __shared__ double red[4][64];
    int w = t >> 6, lane = t & 63;
    for (int task = bid; task < 513; task += G) {
        if (task < 256) {
            int b = task >> 3;
            int a0 = (task & 7) * 64;
            #pragma unroll
            for (int c = 0; c < 4; ++c) {
                int h = t + c * 256;
                float acc = 0.f;
                #pragma unroll 4
                for (int qc = 0; qc < QCH; ++qc)
                    acc += partial[((size_t)qc * NB + b) * HD + h];
                sq[h] = acc;
            }
            __syncthreads();
            int a = a0 + lane;
            const float* wp = Wq + a;
            double c0 = 0.0, c1 = 0.0, c2 = 0.0, c3 = 0.0;
            int hbase = w * 256;
            for (int i = 0; i < 256; i += 4) {
                int h = hbase + i;
                c0 += (double)sq[h]     * (double)wp[(size_t)h * AD];
                c1 += (double)sq[h + 1] * (double)wp[(size_t)(h + 1) * AD];
                c2 += (double)sq[h + 2] * (double)wp[(size_t)(h + 2) * AD];
                c3 += (double)sq[h + 3] * (double)wp[(size_t)(h + 3) * AD];
            }
            red[w][lane] = ((c0 + c1) + (c2 + c3));
            __syncthreads();
            if (t < 64) {
                double s = red[0][t] + red[1][t] + red[2][t] + red[3][t];
                qsum[(size_t)b * AD + a0 + t] = (float)(s + (double)LQ * (double)bq[a0 + t]);
            }
            __syncthreads();
        } else if (task < 512) {
            int h = (task - 256) * 4 + w;            // 4 rows per task, 1024 rows total
            const float4* wr = (const float4*)(Wk + (size_t)h * AD);
            const float4* vv = (const float4*)(Wv);
            double acc = 0.0;
            #pragma unroll
            for (int j = 0; j < 2; ++j) {
                int f = lane + 64 * j;
                float4 w4 = wr[f];
                float4 v4 = vv[f];
                acc += (double)w4.x * (double)v4.x + (double)w4.y * (double)v4.y
                     + (double)w4.z * (double)v4.z + (double)w4.w * (double)v4.w;
            }
            #pragma unroll
            for (int off = 32; off > 0; off >>= 1) acc += __shfl_down(acc, off);
            if (lane == 0) wv_eff[h] = (float)acc;
        } else {
            if (t < 64) {
                const float4* br = (const float4*)(bk);
                const float4* vv = (const float4*)(Wv);
                double acc = 0.0;
                #pragma unroll
                for (int j = 0; j < 2; ++j) {
                    int f = lane + 64 * j;
                    float4 b4 = br[f];
                    float4 v4 = vv[f];
                    acc += (double)b4.x * (double)v4.x + (double)b4.y * (double)v4.y
                         + (double)b4.z * (double)v4.z + (double)b4.w * (double)v4.w;
                }
                #pragma unroll
                for (int off = 32; off > 0; off >>= 1) acc += __shfl_down(acc, off);
                if (lane == 0) c_v[0] = (float)(acc + (double)bv[0]);
            }
        }
    }
}

// ---------------- Phase 3: wk_eff[b][h] = qsum[b]·Wk[h,:] — 1024 tasks x 32 rows ----------------
__device__ __forceinline__ void phase3(int G, int bid, int t,
        const float* __restrict__ qsum, const float* __restrict__ Wk,
        float* __restrict__ wk_eff) {
    int w = t >> 6, lane = t & 63;
    for (int task = bid; task < 1024; task += G) {
        int base = task * 32 + w * 8;
        for (int r = 0; r < 8; ++r) {
            int idx = base + r;                      // 0..32767
            int b = idx >> 10, h = idx & (HD - 1);
            const float4* wr = (const float4*)(Wk + (size_t)h * AD);
            const float4* qs = (const float4*)(qsum + (size_t)b * AD);
            double acc = 0.0;
            #pragma unroll
            for (int j = 0; j < 2; ++j) {
                int f = lane + 64 * j;
                float4 w4 = wr[f];
                float4 q4 = qs[f];
                acc += (double)w4.x * (double)q4.x + (double)w4.y * (double)q4.y
                     + (double)w4.z * (double)q4.z + (double)w4.w * (double)q4.w;
            }
            #pragma unroll
            for (int off = 32; off > 0; off >>= 1) acc += __shfl_down(acc, off);
            if (lane == 0) wk_eff[idx] = (float)acc;
        }
    }
}

// ---------------- Phase 4: scores/vvals — 1024 tasks x 64 keys ----------------
__device__ __forceinline__ void phase4(int G, int bid, int t,
        const float* __restrict__ key, const float* __restrict__ wk_eff,
        const float* __restrict__ wv_eff, const float* __restrict__ c_v,
        float* __restrict__ scores, float* __restrict__ vvals) {
    __shared__ float lwk[HD];
    __shared__ float lwv[HD];
    int w = t >> 6, lane = t & 63;
    for (int task = bid; task < 1024; task += G) {
        int b = task >> 5;                           // 32 tasks per batch
        int k0 = (task & 31) * 64;
        for (int i = t; i < HD; i += 256) {
            lwk[i] = wk_eff[(size_t)b * HD + i];
            lwv[i] = wv_eff[i];
        }
        __syncthreads();
        double cv = (double)c_v[0];
        const float4* lwk4 = (const float4*)lwk;
        const float4* lwv4 = (const float4*)lwv;
        for (int rp = 0; rp < 8; ++rp) {
            int k = k0 + w * 16 + rp * 2;
            const float4* kr0 = (const float4*)(key + ((size_t)b * LK + k) * HD);
            const float4* kr1 = kr0 + (HD / 4);
            double sc0 = 0.0, vv0 = 0.0, sc1 = 0.0, vv1 = 0.0;
            #pragma unroll
            for (int j = 0; j < 4; ++j) {
                int f = lane + 64 * j;
                float4 k0v = kr0[f];
                float4 k1v = kr1[f];
                float4 wk4 = lwk4[f];
                float4 wv4 = lwv4[f];
                sc0 += (double)k0v.x * (double)wk4.x + (double)k0v.y * (double)wk4.y
                     + (double)k0v.z * (double)wk4.z + (double)k0v.w * (double)wk4.w;
                vv0 += (double)k0v.x * (double)wv4.x + (double)k0v.y * (double)wv4.y
                     + (double)k0v.z * (double)wv4.z + (double)k0v.w * (double)wv4.w;
                sc1 += (double)k1v.x * (double)wk4.x + (double)k1v.y * (double)wk4.y
                     + (double)k1v.z * (double)wk4.z + (double)k1v.w * (double)wk4.w;
                vv1 += (double)k1v.x * (double)wv4.x + (double)k1v.y * (double)wv4.y
                     + (double)k1v.z * (double)wv4.z + (double)k1v.w * (double)wv4.w;
            }
            #pragma unroll
            for (int off = 32; off > 0; off >>= 1) {
                sc0 += __shfl_down(sc0, off);
                vv0 += __shfl_down(vv0, off);
                sc1 += __shfl_down(sc1, off);
                vv1 += __shfl_down(vv1, off);
            }
            if (lane == 0) {
                scores[(size_t)b * LK + k]     = (float)sc0;
                vvals [(size_t)b * LK + k]     = (float)(vv0 + cv);
                scores[(size_t)b * LK + k + 1] = (float)sc1;
                vvals [(size_t)b * LK + k + 1] = (float)(vv1 + cv);
            }
        }
        __syncthreads();
    }
}

// ---------------- Phase 5: per-batch softmax + weighted sum ----------------
__device__ __forceinline__ void phase5(int G, int bid, int t,
        const float* __restrict__ scores, const float* __restrict__ vvals,
        float* __restrict__ out) {
    __shared__ float smax_sh[4];
    __shared__ double num_sh[4], den_sh[4];
    int w = t >> 6, lane = t & 63;
    for (int b = bid; b < NB; b += G) {
        const float* sr = scores + (size_t)b * LK;
        const float* vr = vvals  + (size_t)b * LK;
        float m = -INFINITY;
        for (int k = t; k < LK; k += 256) m = fmaxf(m, sr[k]);
        #pragma unroll
        for (int off = 32; off > 0; off >>= 1) m = fmaxf(m, __shfl_down(m, off));
        if (lane == 0) smax_sh[w] = m;
        __syncthreads();
        float gm = fmaxf(fmaxf(smax_sh[0], smax_sh[1]), fmaxf(smax_sh[2], smax_sh[3]));
        double num = 0.0, den = 0.0;
        for (int k = t; k < LK; k += 256) {
            double e = exp((double)(sr[k] - gm));
            den += e;
            num += e * (double)vr[k];
        }
        #pragma unroll
        for (int off = 32; off > 0; off >>= 1) {
            num += __shfl_down(num, off);
            den += __shfl_down(den, off);
        }
        if (lane == 0) { num_sh[w] = num; den_sh[w] = den; }
        __syncthreads();
        if (t == 0) {
            double N = num_sh[0] + num_sh[1] + num_sh[2] + num_sh[3];
            double D = den_sh[0] + den_sh[1] + den_sh[2] + den_sh[3];
            out[b] = (float)(N / D);
        }
        __syncthreads();
    }
}

// ---------------- Cooperative fused kernel ----------------
__global__ void __launch_bounds__(256, 4)
fused_all(const float* __restrict__ query, const float* __restrict__ key,
          const float* __restrict__ Wq, const float* __restrict__ bq,
          const float* __restrict__ Wk, const float* __restrict__ bk,
          const float* __restrict__ Wv, const float* __restrict__ bv,
          float* __restrict__ partial, float* __restrict__ qsum,
          float* __restrict__ wk_eff, float* __restrict__ wv_eff,
          float* __restrict__ c_v, float* __restrict__ scores,
          float* __restrict__ vvals, float* __restrict__ out) {
    cg::grid_group grid = cg::this_grid();
    const int G = gridDim.x, bid = blockIdx.x, t = threadIdx.x;
    phase1(G, bid, t, query, partial);
    grid.sync();
    phase2(G, bid, t, partial, Wq, bq, Wk, Wv, bk, bv, qsum, wv_eff, c_v);
    grid.sync();
    phase3(G, bid, t, qsum, Wk, wk_eff);
    grid.sync();
    phase4(G, bid, t, key, wk_eff, wv_eff, c_v, scores, vvals);
    grid.sync();
    phase5(G, bid, t, scores, vvals, out);
}

// ---------------- Fallback kernels (separate launches, known-good path) ----------------
__global__ void __launch_bounds__(256) kp1(const float* __restrict__ query,
                                           float* __restrict__ partial) {
    phase1(gridDim.x, blockIdx.x, threadIdx.x, query, partial);
}
__global__ void __launch_bounds__(256) kp2(const float* __restrict__ partial,
                                           const float* __restrict__ Wq,
                                           const float* __restrict__ bq,
                                           const float* __restrict__ Wk,
                                           const float* __restrict__ Wv,
                                           const float* __restrict__ bk,
                                           const float* __restrict__ bv,
                                           float* __restrict__ qsum,
                                           float* __restrict__ wv_eff,
                                           float* __restrict__ c_v) {
    phase2(gridDim.x, blockIdx.x, threadIdx.x, partial, Wq, bq, Wk, Wv, bk, bv,
           qsum, wv_eff, c_v);
}
__global__ void __launch_bounds__(256) kp3(const float* __restrict__ qsum,
                                           const float* __restrict__ Wk,
                                           float* __restrict__ wk_eff) {
    phase3(gridDim.x, blockIdx.x, threadIdx.x, qsum, Wk, wk_eff);
}
__global__ void __launch_bounds__(256) kp4(const float* __restrict__ key,
                                           const float* __restrict__ wk_eff,
                                           const float* __restrict__ wv_eff,
                                           const float* __restrict__ c_v,
                                           float* __restrict__ scores,
                                           float* __restrict__ vvals) {
    phase4(gridDim.x, blockIdx.x, threadIdx.x, key, wk_eff, wv_eff, c_v, scores, vvals);
}
__global__ void __launch_bounds__(256) kp5(const float* __restrict__ scores,
                                           const float* __restrict__ vvals,
                                           float* __restrict__ out) {
    phase5(gridDim.x, blockIdx.x, threadIdx.x, scores, vvals, out);
}

extern "C" void kernel_launch(void* const* d_in, const int* in_sizes, int n_in,
                              void* d_out, int out_size, void* d_ws, size_t ws_size,
                              hipStream_t stream) {
    const float* query = (const float*)d_in[0];
    const float* key   = (const float*)d_in[1];
    const float* Wq    = (const float*)d_in[2];
    const float* bq    = (const float*)d_in[3];
    const float* Wk    = (const float*)d_in[4];
    const float* bk    = (const float*)d_in[5];
    const float* Wv    = (const float*)d_in[6];
    const float* bv    = (const float*)d_in[7];
    float* out = (float*)d_out;

    float* ws = (float*)d_ws;
    size_t off = 0;
    float* partial = ws + off; off += (size_t)QCH * NB * HD;  // 4 MB
    float* qsum    = ws + off; off += (size_t)NB * AD;
    float* wk_eff  = ws + off; off += (size_t)NB * HD;
    float* wv_eff  = ws + off; off += (size_t)HD;
    float* c_v     = ws + off; off += 1;
    float* scores  = ws + off; off += (size_t)NB * LK;
    float* vvals   = ws + off; off += (size_t)NB * LK;

    // Host-only capacity query (graph-capture safe).
    int dev = 0;
    (void)hipGetDevice(&dev);
    int numCU = 0;
    (void)hipDeviceGetAttribute(&numCU, hipDeviceAttributeMultiprocessorCount, dev);
    int maxBlk = 0;
    hipError_t occ = hipOccupancyMaxActiveBlocksPerMultiprocessor(
        &maxBlk, (const void*)fused_all, 256, 0);

    hipError_t st = hipErrorUnknown;
    if (occ == hipSuccess && numCU > 0 && maxBlk > 0) {
        int G = maxBlk * numCU;
        if (G > NB * QCH) G = NB * QCH;
        if (G >= 64) {
            void* args[] = {
                (void*)&query, (void*)&key, (void*)&Wq, (void*)&bq,
                (void*)&Wk, (void*)&bk, (void*)&Wv, (void*)&bv,
                (void*)&partial, (void*)&qsum, (void*)&wk_eff, (void*)&wv_eff,
                (void*)&c_v, (void*)&scores, (void*)&vvals, (void*)&out
            };
            st = hipLaunchCooperativeKernel((const void*)fused_all, dim3(G), dim3(256),
                                            args, 0, stream);
        }
    }

    if (st != hipSuccess) {
        // Fallback: 5 separate launches (round-3-equivalent, known good).
        hipLaunchKernelGGL(kp1, dim3(NB * QCH), dim3(256), 0, stream, query, partial);
        hipLaunchKernelGGL(kp2, dim3(513), dim3(256), 0, stream,
                           partial, Wq, bq, Wk, Wv, bk, bv, qsum, wv_eff, c_v);
        hipLaunchKernelGGL(kp3, dim3(1024), dim3(256), 0, stream, qsum, Wk, wk_eff);
        hipLaunchKernelGGL(kp4, dim3(1024), dim3(256), 0, stream,
                           key, wk_eff, wv_eff, c_v, scores, vvals);
        hipLaunchKernelGGL(kp5, dim3(NB), dim3(256), 0, stream, scores, vvals, out);
    }
}

// Round 7
// 329.826 us; speedup vs baseline: 1.2004x; 1.2004x over previous
//
#include <hip/hip_runtime.h>
#include <math.h>

#define NB 32
#define LQ 2048
#define LK 2048
#define HD 1024
#define AD 512
#define QCH 32   // q-chunks for first-stage query reduction (1024 stream blocks)

// =====================================================================
// K1: blocks 0..255   : MT tile GEMM  MT[h][h'] = Wk[h,:]·Wq[h',:]
//                       (+ aux: wv_eff, ck on pb==0 blocks; c_v on block 0)
//     blocks 256..1279: query partial-reduce (streaming)
// MT blocks come FIRST so they are resident alongside streaming blocks
// and their VALU work hides under the memory-bound query stream.
// =====================================================================
__global__ void __launch_bounds__(256, 4)
k1_main(const float* __restrict__ query, const float* __restrict__ Wq,
        const float* __restrict__ Wk, const float* __restrict__ Wv,
        const float* __restrict__ bq, const float* __restrict__ bk,
        const float* __restrict__ bv, float* __restrict__ partial,
        float* __restrict__ MT, float* __restrict__ wv_eff,
        float* __restrict__ ck, float* __restrict__ c_v) {
    __shared__ float wq_l[128][33];
    __shared__ float wk_l[32][33];
    const int bid = blockIdx.x;
    const int t = threadIdx.x;

    if (bid >= 256) {
        // ---- streaming phase: partial[qc][b][h] = sum over 64-row q-chunk ----
        int task = bid - 256;
        int b = task / QCH, qc = task % QCH;
        const int QPC = LQ / QCH;        // 64 rows
        float4 a0 = {0.f, 0.f, 0.f, 0.f};
        float4 a1 = {0.f, 0.f, 0.f, 0.f};
        const float4* src = (const float4*)(query + ((size_t)b * LQ + (size_t)qc * QPC) * HD);
        for (int q = 0; q < QPC; q += 2) {
            float4 v0 = src[(size_t)q * (HD / 4) + t];
            float4 v1 = src[(size_t)(q + 1) * (HD / 4) + t];
            a0.x += v0.x; a0.y += v0.y; a0.z += v0.z; a0.w += v0.w;
            a1.x += v1.x; a1.y += v1.y; a1.z += v1.z; a1.w += v1.w;
        }
        float4 acc = {a0.x + a1.x, a0.y + a1.y, a0.z + a1.z, a0.w + a1.w};
        ((float4*)(partial + ((size_t)qc * NB + b) * HD))[t] = acc;
        return;
    }

    // ---- MT tile GEMM: tile = 32 h-rows x 128 h'-cols, K = 512 (a) ----
    const int hb = bid >> 3;             // 0..31 -> h0 = hb*32
    const int pb = bid & 7;              // 0..7  -> h'0 = pb*128
    const int hgrp = t >> 5;             // 0..7
    const int pgrp = t & 31;             // 0..31
    float acc[4][4] = {{0.f}};
    for (int ac = 0; ac < 16; ++ac) {    // 16 chunks of 32 a
        for (int s = t; s < 128 * 32; s += 256) {
            int row = s >> 5, a = s & 31;
            wq_l[row][a] = Wq[(size_t)(pb * 128 + row) * AD + ac * 32 + a];
        }
        for (int s = t; s < 32 * 32; s += 256) {
            int row = s >> 5, a = s & 31;
            wk_l[row][a] = Wk[(size_t)(hb * 32 + row) * AD + ac * 32 + a];
        }
        __syncthreads();
        #pragma unroll 8
        for (int a = 0; a < 32; ++a) {
            float k0 = wk_l[hgrp][a],      k1 = wk_l[hgrp + 8][a],
                  k2 = wk_l[hgrp + 16][a], k3 = wk_l[hgrp + 24][a];
            float q0 = wq_l[pgrp][a],      q1 = wq_l[pgrp + 32][a],
                  q2 = wq_l[pgrp + 64][a], q3 = wq_l[pgrp + 96][a];
            acc[0][0] += k0*q0; acc[0][1] += k0*q1; acc[0][2] += k0*q2; acc[0][3] += k0*q3;
            acc[1][0] += k1*q0; acc[1][1] += k1*q1; acc[1][2] += k1*q2; acc[1][3] += k1*q3;
            acc[2][0] += k2*q0; acc[2][1] += k2*q1; acc[2][2] += k2*q2; acc[2][3] += k2*q3;
            acc[3][0] += k3*q0; acc[3][1] += k3*q1; acc[3][2] += k3*q2; acc[3][3] += k3*q3;
        }
        __syncthreads();
    }
    #pragma unroll
    for (int i = 0; i < 4; ++i)
        #pragma unroll
        for (int j = 0; j < 4; ++j)
            MT[(size_t)(hb * 32 + hgrp + 8 * i) * HD + pb * 128 + pgrp + 32 * j] = acc[i][j];

    // ---- aux: wv_eff[h] = Wk[h,:]·Wv ; ck[h] = LQ*(bq·Wk[h,:]) (pb==0 blocks) ----
    if (pb == 0) {
        int w = t >> 6, lane = t & 63;
        const float4* vv4 = (const float4*)Wv;
        const float4* bq4 = (const float4*)bq;
        for (int rr = 0; rr < 8; ++rr) {
            int h = hb * 32 + w * 8 + rr;
            const float4* wr = (const float4*)(Wk + (size_t)h * AD);
            double a1 = 0.0, a2 = 0.0;
            #pragma unroll
            for (int j = 0; j < 2; ++j) {
                int f = lane + 64 * j;
                float4 w4 = wr[f];
                float4 v4 = vv4[f];
                float4 b4 = bq4[f];
                a1 += (double)w4.x * v4.x + (double)w4.y * v4.y
                    + (double)w4.z * v4.z + (double)w4.w * v4.w;
                a2 += (double)b4.x * w4.x + (double)b4.y * w4.y
                    + (double)b4.z * w4.z + (double)b4.w * w4.w;
            }
            #pragma unroll
            for (int off = 32; off > 0; off >>= 1) {
                a1 += __shfl_down(a1, off);
                a2 += __shfl_down(a2, off);
            }
            if (lane == 0) {
                wv_eff[h] = (float)a1;
                ck[h] = (float)((double)LQ * a2);
            }
        }
    }
    if (bid == 0 && t < 64) {
        int lane = t;
        const float4* br = (const float4*)bk;
        const float4* vv4 = (const float4*)Wv;
        double acc2 = 0.0;
        #pragma unroll
        for (int j = 0; j < 2; ++j) {
            int f = lane + 64 * j;
            float4 b4 = br[f];
            float4 v4 = vv4[f];
            acc2 += (double)b4.x * v4.x + (double)b4.y * v4.y
                  + (double)b4.z * v4.z + (double)b4.w * v4.w;
        }
        #pragma unroll
        for (int off = 32; off > 0; off >>= 1) acc2 += __shfl_down(acc2, off);
        if (lane == 0) c_v[0] = (float)(acc2 + (double)bv[0]);
    }
}

// =====================================================================
// K2: 256 blocks (b = bid>>3, h-chunk = bid&7):
//   stage s_q[b] in LDS (reduce partial), then
//   wk_eff[b][h] = s_q[b]·MT[h,:] + ck[h]   (wave-per-row)
//   block 0 zeroes the fold counters for K3.
// =====================================================================
__global__ void __launch_bounds__(256)
k2_wkeff(const float* __restrict__ partial, const float* __restrict__ MT,
         const float* __restrict__ ck, float* __restrict__ wk_eff,
         int* __restrict__ cnt) {
    __shared__ float sq[HD];
    const int bid = blockIdx.x;
    const int t = threadIdx.x;
    const int b = bid >> 3, hc = bid & 7;
    if (bid == 0 && t < NB) cnt[t] = 0;
    for (int h = t; h < HD; h += 256) {
        float acc = 0.f;
        #pragma unroll 4
        for (int qc = 0; qc < QCH; ++qc)
            acc += partial[((size_t)qc * NB + b) * HD + h];
        sq[h] = acc;
    }
    __syncthreads();
    int w = t >> 6, lane = t & 63;
    const float4* sq4 = (const float4*)sq;
    for (int rr = 0; rr < 32; ++rr) {
        int h = hc * 128 + w * 32 + rr;
        const float4* m4 = (const float4*)(MT + (size_t)h * HD);
        double acc = 0.0;
        #pragma unroll
        for (int f0 = 0; f0 < 4; ++f0) {
            int f = lane + 64 * f0;
            float4 m = m4[f];
            float4 s = sq4[f];
            acc += (double)m.x * s.x + (double)m.y * s.y
                 + (double)m.z * s.z + (double)m.w * s.w;
        }
        #pragma unroll
        for (int off = 32; off > 0; off >>= 1) acc += __shfl_down(acc, off);
        if (lane == 0) wk_eff[(size_t)b * HD + h] = (float)(acc + (double)ck[h]);
    }
}

// =====================================================================
// K3: 2048 blocks, 32 keys each: scores/vvals; the LAST block per batch
//     (atomicAdd counter + __threadfence) folds the softmax -> out[b].
// =====================================================================
__global__ void __launch_bounds__(256)
k3_scores(const float* __restrict__ key, const float* __restrict__ wk_eff,
          const float* __restrict__ wv_eff, const float* __restrict__ c_v,
          float* __restrict__ scores, float* __restrict__ vvals,
          int* __restrict__ cnt, float* __restrict__ out) {
    __shared__ float lwk[HD];
    __shared__ float lwv[HD];
    __shared__ int lastFlag;
    __shared__ float smax_sh[4];
    __shared__ double num_sh[4], den_sh[4];
    const int bid = blockIdx.x;
    const int b = bid >> 6;              // 64 blocks per batch
    const int k0 = (bid & 63) * 32;
    const int t = threadIdx.x;
    for (int i = t; i < HD; i += 256) {
        lwk[i] = wk_eff[(size_t)b * HD + i];
        lwv[i] = wv_eff[i];
    }
    __syncthreads();
    int w = t >> 6, lane = t & 63;
    double cv = (double)c_v[0];
    const float4* lwk4 = (const float4*)lwk;
    const float4* lwv4 = (const float4*)lwv;
    for (int rp = 0; rp < 4; ++rp) {
        int k = k0 + w * 8 + rp * 2;
        const float4* kr0 = (const float4*)(key + ((size_t)b * LK + k) * HD);
        const float4* kr1 = kr0 + (HD / 4);
        double sc0 = 0.0, vv0 = 0.0, sc1 = 0.0, vv1 = 0.0;
        #pragma unroll
        for (int j = 0; j < 4; ++j) {
            int f = lane + 64 * j;
            float4 k0v = kr0[f];
            float4 k1v = kr1[f];
            float4 wk4 = lwk4[f];
            float4 wv4 = lwv4[f];
            sc0 += (double)k0v.x * wk4.x + (double)k0v.y * wk4.y
                 + (double)k0v.z * wk4.z + (double)k0v.w * wk4.w;
            vv0 += (double)k0v.x * wv4.x + (double)k0v.y * wv4.y
                 + (double)k0v.z * wv4.z + (double)k0v.w * wv4.w;
            sc1 += (double)k1v.x * wk4.x + (double)k1v.y * wk4.y
                 + (double)k1v.z * wk4.z + (double)k1v.w * wk4.w;
            vv1 += (double)k1v.x * wv4.x + (double)k1v.y * wv4.y
                 + (double)k1v.z * wv4.z + (double)k1v.w * wv4.w;
        }
        #pragma unroll
        for (int off = 32; off > 0; off >>= 1) {
            sc0 += __shfl_down(sc0, off);
            vv0 += __shfl_down(vv0, off);
            sc1 += __shfl_down(sc1, off);
            vv1 += __shfl_down(vv1, off);
        }
        if (lane == 0) {
            scores[(size_t)b * LK + k]     = (float)sc0;
            vvals [(size_t)b * LK + k]     = (float)(vv0 + cv);
            scores[(size_t)b * LK + k + 1] = (float)sc1;
            vvals [(size_t)b * LK + k + 1] = (float)(vv1 + cv);
        }
    }
    __syncthreads();
    if (t == 0) {
        __threadfence();                              // release our scores/vvals
        int old = atomicAdd(&cnt[b], 1);              // device-scope by default
        lastFlag = (old == 63) ? 1 : 0;
    }
    __syncthreads();
    if (!lastFlag) return;
    __threadfence();                                  // acquire others' scores/vvals

    // fold: softmax over scores[b], weighted sum of vvals[b]
    const float* sr = scores + (size_t)b * LK;
    const float* vr = vvals  + (size_t)b * LK;
    float m = -INFINITY;
    for (int k = t; k < LK; k += 256) m = fmaxf(m, sr[k]);
    #pragma unroll
    for (int off = 32; off > 0; off >>= 1) m = fmaxf(m, __shfl_down(m, off));
    if (lane == 0) smax_sh[w] = m;
    __syncthreads();
    float gm = fmaxf(fmaxf(smax_sh[0], smax_sh[1]), fmaxf(smax_sh[2], smax_sh[3]));
    double num = 0.0, den = 0.0;
    for (int k = t; k < LK; k += 256) {
        double e = exp((double)(sr[k] - gm));
        den += e;
        num += e * (double)vr[k];
    }
    #pragma unroll
    for (int off = 32; off > 0; off >>= 1) {
        num += __shfl_down(num, off);
        den += __shfl_down(den, off);
    }
    if (lane == 0) { num_sh[w] = num; den_sh[w] = den; }
    __syncthreads();
    if (t == 0) {
        double N = num_sh[0] + num_sh[1] + num_sh[2] + num_sh[3];
        double D = den_sh[0] + den_sh[1] + den_sh[2] + den_sh[3];
        out[b] = (float)(N / D);
    }
}

// =====================================================================
// Fallback path (only if ws_size is too small for MT): round-3 structure.
// =====================================================================
__global__ void __launch_bounds__(256)
fbA(const float* __restrict__ query, const float* __restrict__ Wk,
    const float* __restrict__ Wv, const float* __restrict__ bk,
    const float* __restrict__ bv, float* __restrict__ partial,
    float* __restrict__ wv_eff, float* __restrict__ c_v) {
    int bid = blockIdx.x;
    int t = threadIdx.x;
    if (bid < NB * QCH) {
        int b = bid / QCH, qc = bid % QCH;
        const int QPC = LQ / QCH;
        float4 a0 = {0.f,0.f,0.f,0.f}, a1 = {0.f,0.f,0.f,0.f};
        const float4* src = (const float4*)(query + ((size_t)b * LQ + (size_t)qc * QPC) * HD);
        for (int q = 0; q < QPC; q += 2) {
            float4 v0 = src[(size_t)q * (HD / 4) + t];
            float4 v1 = src[(size_t)(q + 1) * (HD / 4) + t];
            a0.x += v0.x; a0.y += v0.y; a0.z += v0.z; a0.w += v0.w;
            a1.x += v1.x; a1.y += v1.y; a1.z += v1.z; a1.w += v1.w;
        }
        float4 acc = {a0.x + a1.x, a0.y + a1.y, a0.z + a1.z, a0.w + a1.w};
        ((float4*)(partial + ((size_t)qc * NB + b) * HD))[t] = acc;
    } else if (bid < NB * QCH + 16) {
        int w = t >> 6, lane = t & 63;
        int gw = (bid - NB * QCH) * 4 + w;
        const float4* vv = (const float4*)Wv;
        for (int r = 0; r < 16; ++r) {
            int h = gw * 16 + r;
            const float4* wr = (const float4*)(Wk + (size_t)h * AD);
            double acc = 0.0;
            #pragma unroll
            for (int j = 0; j < 2; ++j) {
                int f = lane + 64 * j;
                float4 w4 = wr[f];
                float4 v4 = vv[f];
                acc += (double)w4.x * v4.x + (double)w4.y * v4.y
                     + (double)w4.z * v4.z + (double)w4.w * v4.w;
            }
            #pragma unroll
            for (int off = 32; off > 0; off >>= 1) acc += __shfl_down(acc, off);
            if (lane == 0) wv_eff[h] = (float)acc;
        }
    } else if (t < 64) {
        int lane = t;
        const float4* br = (const float4*)bk;
        const float4* vv = (const float4*)Wv;
        double acc = 0.0;
        #pragma unroll
        for (int j = 0; j < 2; ++j) {
            int f = lane + 64 * j;
            float4 b4 = br[f];
            float4 v4 = vv[f];
            acc += (double)b4.x * v4.x + (double)b4.y * v4.y
                 + (double)b4.z * v4.z + (double)b4.w * v4.w;
        }
        #pragma unroll
        for (int off = 32; off > 0; off >>= 1) acc += __shfl_down(acc, off);
        if (lane == 0) c_v[0] = (float)(acc + (double)bv[0]);
    }
}

__global__ void __launch_bounds__(256)
fbB(const float* __restrict__ partial, const float* __restrict__ Wq,
    const float* __restrict__ bq, float* __restrict__ qsum, int* __restrict__ cnt) {
    __shared__ float sq[HD];
    __shared__ double red[4][64];
    int b = blockIdx.x >> 3;
    int a0 = (blockIdx.x & 7) * 64;
    int t = threadIdx.x;
    if (blockIdx.x == 0 && t < NB) cnt[t] = 0;
    #pragma unroll
    for (int c = 0; c < 4; ++c) {
        int h = t + c * 256;
        float acc = 0.f;
        #pragma unroll 4
        for (int qc = 0; qc < QCH; ++qc)
            acc += partial[((size_t)qc * NB + b) * HD + h];
        sq[h] = acc;
    }
    __syncthreads();
    int w = t >> 6, lane = t & 63;
    int a = a0 + lane;
    const float* wp = Wq + a;
    double c0 = 0.0, c1 = 0.0, c2 = 0.0, c3 = 0.0;
    int hbase = w * 256;
    for (int i = 0; i < 256; i += 4) {
        int h = hbase + i;
        c0 += (double)sq[h]     * wp[(size_t)h * AD];
        c1 += (double)sq[h + 1] * wp[(size_t)(h + 1) * AD];
        c2 += (double)sq[h + 2] * wp[(size_t)(h + 2) * AD];
        c3 += (double)sq[h + 3] * wp[(size_t)(h + 3) * AD];
    }
    red[w][lane] = ((c0 + c1) + (c2 + c3));
    __syncthreads();
    if (t < 64) {
        double s = red[0][t] + red[1][t] + red[2][t] + red[3][t];
        qsum[(size_t)b * AD + a0 + t] = (float)(s + (double)LQ * bq[a0 + t]);
    }
}

__global__ void __launch_bounds__(256)
fbC(const float* __restrict__ qsum, const float* __restrict__ Wk,
    float* __restrict__ wk_eff) {
    int w = threadIdx.x >> 6, lane = threadIdx.x & 63;
    int widx = blockIdx.x * 4 + w;
    int b = widx >> 10, h = widx & (HD - 1);
    const float4* wr = (const float4*)(Wk + (size_t)h * AD);
    const float4* qs = (const float4*)(qsum + (size_t)b * AD);
    double acc = 0.0;
    #pragma unroll
    for (int j = 0; j < 2; ++j) {
        int f = lane + 64 * j;
        float4 w4 = wr[f];
        float4 q4 = qs[f];
        acc += (double)w4.x * q4.x + (double)w4.y * q4.y
             + (double)w4.z * q4.z + (double)w4.w * q4.w;
    }
    #pragma unroll
    for (int off = 32; off > 0; off >>= 1) acc += __shfl_down(acc, off);
    if (lane == 0) wk_eff[widx] = (float)acc;
}

extern "C" void kernel_launch(void* const* d_in, const int* in_sizes, int n_in,
                              void* d_out, int out_size, void* d_ws, size_t ws_size,
                              hipStream_t stream) {
    const float* query = (const float*)d_in[0];
    const float* key   = (const float*)d_in[1];
    const float* Wq    = (const float*)d_in[2];
    const float* bq    = (const float*)d_in[3];
    const float* Wk    = (const float*)d_in[4];
    const float* bk    = (const float*)d_in[5];
    const float* Wv    = (const float*)d_in[6];
    const float* bv    = (const float*)d_in[7];
    float* out = (float*)d_out;

    float* ws = (float*)d_ws;
    size_t off = 0;
    float* partial = ws + off; off += (size_t)QCH * NB * HD;   // 4 MB
    float* MT      = ws + off; off += (size_t)HD * HD;         // 4 MB
    float* wk_eff  = ws + off; off += (size_t)NB * HD;
    float* wv_eff  = ws + off; off += (size_t)HD;
    float* ck      = ws + off; off += (size_t)HD;
    float* c_v     = ws + off; off += 1;
    float* scores  = ws + off; off += (size_t)NB * LK;
    float* vvals   = ws + off; off += (size_t)NB * LK;
    int*   cnt     = (int*)(ws + off); off += NB;
    size_t need_main = off * sizeof(float);

    if (ws_size >= need_main) {
        hipLaunchKernelGGL(k1_main, dim3(256 + NB * QCH), dim3(256), 0, stream,
                           query, Wq, Wk, Wv, bq, bk, bv,
                           partial, MT, wv_eff, ck, c_v);
        hipLaunchKernelGGL(k2_wkeff, dim3(256), dim3(256), 0, stream,
                           partial, MT, ck, wk_eff, cnt);
        hipLaunchKernelGGL(k3_scores, dim3(NB * (LK / 32)), dim3(256), 0, stream,
                           key, wk_eff, wv_eff, c_v, scores, vvals, cnt, out);
    } else {
        // fallback: round-3 structure; qsum overlays the MT region
        float* qsum = MT;
        hipLaunchKernelGGL(fbA, dim3(NB * QCH + 16 + 1), dim3(256), 0, stream,
                           query, Wk, Wv, bk, bv, partial, wv_eff, c_v);
        hipLaunchKernelGGL(fbB, dim3(256), dim3(256), 0, stream,
                           partial, Wq, bq, qsum, cnt);
        hipLaunchKernelGGL(fbC, dim3(NB * HD / 4), dim3(256), 0, stream,
                           qsum, Wk, wk_eff);
        hipLaunchKernelGGL(k3_scores, dim3(NB * (LK / 32)), dim3(256), 0, stream,
                           key, wk_eff, wv_eff, c_v, scores, vvals, cnt, out);
    }
}

// Round 8
// 211.325 us; speedup vs baseline: 1.8735x; 1.5608x over previous
//
#include <hip/hip_runtime.h>
#include <math.h>

#define NB 32
#define LQ 2048
#define LK 2048
#define HD 1024
#define AD 512
#define QCH 64   // q-chunks for first-stage query reduction (2048 stream blocks)

// =====================================================================
// K1: blocks 0..2047  : partial[qc][b][h] = sum over 32-row q-chunk (4 rows in flight)
//     blocks 2048..2063: wv_eff[h] = Wk[h,:]·Wv (wave-per-row)
//     block  2064      : c_v = bk·Wv + bv
// =====================================================================
__global__ void __launch_bounds__(256)
k1_stream(const float* __restrict__ query, const float* __restrict__ Wk,
          const float* __restrict__ Wv, const float* __restrict__ bk,
          const float* __restrict__ bv, float* __restrict__ partial,
          float* __restrict__ wv_eff, float* __restrict__ c_v) {
    const int bid = blockIdx.x;
    const int t = threadIdx.x;
    if (bid < NB * QCH) {
        int b = bid / QCH, qc = bid % QCH;
        const int QPC = LQ / QCH;        // 32 rows per chunk
        float4 a0 = {0.f,0.f,0.f,0.f}, a1 = {0.f,0.f,0.f,0.f};
        float4 a2 = {0.f,0.f,0.f,0.f}, a3 = {0.f,0.f,0.f,0.f};
        const float4* src = (const float4*)(query + ((size_t)b * LQ + (size_t)qc * QPC) * HD);
        for (int q = 0; q < QPC; q += 4) {
            float4 v0 = src[(size_t)(q + 0) * (HD / 4) + t];
            float4 v1 = src[(size_t)(q + 1) * (HD / 4) + t];
            float4 v2 = src[(size_t)(q + 2) * (HD / 4) + t];
            float4 v3 = src[(size_t)(q + 3) * (HD / 4) + t];
            a0.x += v0.x; a0.y += v0.y; a0.z += v0.z; a0.w += v0.w;
            a1.x += v1.x; a1.y += v1.y; a1.z += v1.z; a1.w += v1.w;
            a2.x += v2.x; a2.y += v2.y; a2.z += v2.z; a2.w += v2.w;
            a3.x += v3.x; a3.y += v3.y; a3.z += v3.z; a3.w += v3.w;
        }
        float4 acc = {(a0.x + a1.x) + (a2.x + a3.x), (a0.y + a1.y) + (a2.y + a3.y),
                      (a0.z + a1.z) + (a2.z + a3.z), (a0.w + a1.w) + (a2.w + a3.w)};
        ((float4*)(partial + ((size_t)qc * NB + b) * HD))[t] = acc;
    } else if (bid < NB * QCH + 16) {
        int w = t >> 6, lane = t & 63;
        int gw = (bid - NB * QCH) * 4 + w;           // 0..63
        const float4* vv = (const float4*)Wv;
        for (int r = 0; r < 16; ++r) {
            int h = gw * 16 + r;
            const float4* wr = (const float4*)(Wk + (size_t)h * AD);
            double acc = 0.0;
            #pragma unroll
            for (int j = 0; j < 2; ++j) {
                int f = lane + 64 * j;               // covers AD/4 = 128
                float4 w4 = wr[f];
                float4 v4 = vv[f];
                acc += (double)w4.x * v4.x + (double)w4.y * v4.y
                     + (double)w4.z * v4.z + (double)w4.w * v4.w;
            }
            #pragma unroll
            for (int off = 32; off > 0; off >>= 1) acc += __shfl_down(acc, off);
            if (lane == 0) wv_eff[h] = (float)acc;
        }
    } else if (t < 64) {
        int lane = t;
        const float4* br = (const float4*)bk;
        const float4* vv = (const float4*)Wv;
        double acc = 0.0;
        #pragma unroll
        for (int j = 0; j < 2; ++j) {
            int f = lane + 64 * j;
            float4 b4 = br[f];
            float4 v4 = vv[f];
            acc += (double)b4.x * v4.x + (double)b4.y * v4.y
                 + (double)b4.z * v4.z + (double)b4.w * v4.w;
        }
        #pragma unroll
        for (int off = 32; off > 0; off >>= 1) acc += __shfl_down(acc, off);
        if (lane == 0) c_v[0] = (float)(acc + (double)bv[0]);
    }
}

// =====================================================================
// K2: 32 blocks x 512 threads, one block per batch b:
//   Phase A: s_q[b][:]   = reduce partial over qc   (LDS)
//   Phase B: qsum[a]     = s_q·Wq[:,a] + LQ*bq[a]   (LDS only, thread-per-a)
//   Phase C: wk_eff[b][h]= qsum·Wk[h,:]             (8 waves, 2 rows in flight)
// No global qsum, no MT, no fences.
// =====================================================================
__global__ void __launch_bounds__(512)
k2_qk(const float* __restrict__ partial, const float* __restrict__ Wq,
      const float* __restrict__ bq, const float* __restrict__ Wk,
      float* __restrict__ wk_eff) {
    __shared__ float sq[HD];     // 4 KB
    __shared__ float qs[AD];     // 2 KB
    const int b = blockIdx.x;
    const int t = threadIdx.x;   // 512

    // Phase A: 512 threads x float2 covers HD=1024
    {
        float ax = 0.f, ay = 0.f;
        for (int qc = 0; qc < QCH; ++qc) {
            const float* p = partial + ((size_t)qc * NB + b) * HD + 2 * t;
            ax += p[0];
            ay += p[1];
        }
        sq[2 * t] = ax;
        sq[2 * t + 1] = ay;
    }
    __syncthreads();

    // Phase B: thread t -> column a = t of Wq (coalesced across threads per h)
    {
        int a = t;
        const float* wp = Wq + a;
        double c0 = 0.0, c1 = 0.0;
        for (int h = 0; h < HD; h += 2) {
            c0 += (double)sq[h]     * wp[(size_t)h * AD];
            c1 += (double)sq[h + 1] * wp[(size_t)(h + 1) * AD];
        }
        qs[a] = (float)(c0 + c1 + (double)LQ * (double)bq[a]);
    }
    __syncthreads();

    // Phase C: 8 waves x 128 rows, 2 rows in flight, shuffle reduce
    int w = t >> 6, lane = t & 63;
    const float4* qs4 = (const float4*)qs;
    for (int r = 0; r < 128; r += 2) {
        int h0 = w * 128 + r;
        const float4* r0 = (const float4*)(Wk + (size_t)h0 * AD);
        const float4* r1 = (const float4*)(Wk + (size_t)(h0 + 1) * AD);
        double a0 = 0.0, a1 = 0.0;
        #pragma unroll
        for (int j = 0; j < 2; ++j) {
            int f = lane + 64 * j;
            float4 w0 = r0[f];
            float4 w1 = r1[f];
            float4 q4 = qs4[f];
            a0 += (double)w0.x * q4.x + (double)w0.y * q4.y
                + (double)w0.z * q4.z + (double)w0.w * q4.w;
            a1 += (double)w1.x * q4.x + (double)w1.y * q4.y
                + (double)w1.z * q4.z + (double)w1.w * q4.w;
        }
        #pragma unroll
        for (int off = 32; off > 0; off >>= 1) {
            a0 += __shfl_down(a0, off);
            a1 += __shfl_down(a1, off);
        }
        if (lane == 0) {
            wk_eff[(size_t)b * HD + h0]     = (float)a0;
            wk_eff[(size_t)b * HD + h0 + 1] = (float)a1;
        }
    }
}

// =====================================================================
// K3: 2048 blocks, 32 keys each: scores = key·wk_eff[b], vvals = key·wv_eff + c_v
//     (proven round-2/3 pattern; NO fold, NO fences)
// =====================================================================
__global__ void __launch_bounds__(256)
k3_scores(const float* __restrict__ key, const float* __restrict__ wk_eff,
          const float* __restrict__ wv_eff, const float* __restrict__ c_v,
          float* __restrict__ scores, float* __restrict__ vvals) {
    __shared__ float lwk[HD];
    __shared__ float lwv[HD];
    const int bid = blockIdx.x;
    const int b = bid >> 6;              // 64 blocks per batch
    const int k0 = (bid & 63) * 32;
    const int t = threadIdx.x;
    for (int i = t; i < HD; i += 256) {
        lwk[i] = wk_eff[(size_t)b * HD + i];
        lwv[i] = wv_eff[i];
    }
    __syncthreads();
    int w = t >> 6, lane = t & 63;
    double cv = (double)c_v[0];
    const float4* lwk4 = (const float4*)lwk;
    const float4* lwv4 = (const float4*)lwv;
    for (int rp = 0; rp < 4; ++rp) {
        int k = k0 + w * 8 + rp * 2;
        const float4* kr0 = (const float4*)(key + ((size_t)b * LK + k) * HD);
        const float4* kr1 = kr0 + (HD / 4);
        double sc0 = 0.0, vv0 = 0.0, sc1 = 0.0, vv1 = 0.0;
        #pragma unroll
        for (int j = 0; j < 4; ++j) {
            int f = lane + 64 * j;
            float4 k0v = kr0[f];
            float4 k1v = kr1[f];
            float4 wk4 = lwk4[f];
            float4 wv4 = lwv4[f];
            sc0 += (double)k0v.x * wk4.x + (double)k0v.y * wk4.y
                 + (double)k0v.z * wk4.z + (double)k0v.w * wk4.w;
            vv0 += (double)k0v.x * wv4.x + (double)k0v.y * wv4.y
                 + (double)k0v.z * wv4.z + (double)k0v.w * wv4.w;
            sc1 += (double)k1v.x * wk4.x + (double)k1v.y * wk4.y
                 + (double)k1v.z * wk4.z + (double)k1v.w * wk4.w;
            vv1 += (double)k1v.x * wv4.x + (double)k1v.y * wv4.y
                 + (double)k1v.z * wv4.z + (double)k1v.w * wv4.w;
        }
        #pragma unroll
        for (int off = 32; off > 0; off >>= 1) {
            sc0 += __shfl_down(sc0, off);
            vv0 += __shfl_down(vv0, off);
            sc1 += __shfl_down(sc1, off);
            vv1 += __shfl_down(vv1, off);
        }
        if (lane == 0) {
            scores[(size_t)b * LK + k]     = (float)sc0;
            vvals [(size_t)b * LK + k]     = (float)(vv0 + cv);
            scores[(size_t)b * LK + k + 1] = (float)sc1;
            vvals [(size_t)b * LK + k + 1] = (float)(vv1 + cv);
        }
    }
}

// =====================================================================
// K4: per-batch softmax over scores, weighted sum of vvals -> out[b]
// =====================================================================
__global__ void __launch_bounds__(256)
k4_softmax(const float* __restrict__ scores, const float* __restrict__ vvals,
           float* __restrict__ out) {
    int b = blockIdx.x;
    int t = threadIdx.x;
    __shared__ float smax_sh[4];
    __shared__ double num_sh[4], den_sh[4];
    const float* sr = scores + (size_t)b * LK;
    const float* vr = vvals  + (size_t)b * LK;
    float m = -INFINITY;
    for (int k = t; k < LK; k += 256) m = fmaxf(m, sr[k]);
    #pragma unroll
    for (int off = 32; off > 0; off >>= 1) m = fmaxf(m, __shfl_down(m, off));
    int w = t >> 6, lane = t & 63;
    if (lane == 0) smax_sh[w] = m;
    __syncthreads();
    float gm = fmaxf(fmaxf(smax_sh[0], smax_sh[1]), fmaxf(smax_sh[2], smax_sh[3]));
    double num = 0.0, den = 0.0;
    for (int k = t; k < LK; k += 256) {
        double e = exp((double)(sr[k] - gm));
        den += e;
        num += e * (double)vr[k];
    }
    #pragma unroll
    for (int off = 32; off > 0; off >>= 1) {
        num += __shfl_down(num, off);
        den += __shfl_down(den, off);
    }
    if (lane == 0) { num_sh[w] = num; den_sh[w] = den; }
    __syncthreads();
    if (t == 0) {
        double N = num_sh[0] + num_sh[1] + num_sh[2] + num_sh[3];
        double D = den_sh[0] + den_sh[1] + den_sh[2] + den_sh[3];
        out[b] = (float)(N / D);
    }
}

extern "C" void kernel_launch(void* const* d_in, const int* in_sizes, int n_in,
                              void* d_out, int out_size, void* d_ws, size_t ws_size,
                              hipStream_t stream) {
    const float* query = (const float*)d_in[0];
    const float* key   = (const float*)d_in[1];
    const float* Wq    = (const float*)d_in[2];
    const float* bq    = (const float*)d_in[3];
    const float* Wk    = (const float*)d_in[4];
    const float* bk    = (const float*)d_in[5];
    const float* Wv    = (const float*)d_in[6];
    const float* bv    = (const float*)d_in[7];
    float* out = (float*)d_out;

    float* ws = (float*)d_ws;
    size_t off = 0;
    float* partial = ws + off; off += (size_t)QCH * NB * HD;   // 8 MB
    float* wk_eff  = ws + off; off += (size_t)NB * HD;
    float* wv_eff  = ws + off; off += (size_t)HD;
    float* c_v     = ws + off; off += 1;
    float* scores  = ws + off; off += (size_t)NB * LK;
    float* vvals   = ws + off; off += (size_t)NB * LK;

    hipLaunchKernelGGL(k1_stream, dim3(NB * QCH + 16 + 1), dim3(256), 0, stream,
                       query, Wk, Wv, bk, bv, partial, wv_eff, c_v);
    hipLaunchKernelGGL(k2_qk, dim3(NB), dim3(512), 0, stream,
                       partial, Wq, bq, Wk, wk_eff);
    hipLaunchKernelGGL(k3_scores, dim3(NB * (LK / 32)), dim3(256), 0, stream,
                       key, wk_eff, wv_eff, c_v, scores, vvals);
    hipLaunchKernelGGL(k4_softmax, dim3(NB), dim3(256), 0, stream,
                       scores, vvals, out);
}

// Round 9
// 147.949 us; speedup vs baseline: 2.6761x; 1.4284x over previous
//
#include <hip/hip_runtime.h>
#include <math.h>

#define NB 32
#define LQ 2048
#define LK 2048
#define HD 1024
#define AD 512
#define QCH 32   // q-chunks for first-stage query reduction (1024 stream blocks)

// =====================================================================
// K1: blocks 0..1023   : partial[qc][b][h] = sum over 64-row q-chunk (4 rows in flight)
//     blocks 1024..1039: wv_eff[h] = Wk[h,:]·Wv (wave-per-row)
//     block  1040      : c_v = bk·Wv + bv
// =====================================================================
__global__ void __launch_bounds__(256)
k1_stream(const float* __restrict__ query, const float* __restrict__ Wk,
          const float* __restrict__ Wv, const float* __restrict__ bk,
          const float* __restrict__ bv, float* __restrict__ partial,
          float* __restrict__ wv_eff, float* __restrict__ c_v) {
    const int bid = blockIdx.x;
    const int t = threadIdx.x;
    if (bid < NB * QCH) {
        int b = bid / QCH, qc = bid % QCH;
        const int QPC = LQ / QCH;        // 64 rows per chunk
        float4 a0 = {0.f,0.f,0.f,0.f}, a1 = {0.f,0.f,0.f,0.f};
        float4 a2 = {0.f,0.f,0.f,0.f}, a3 = {0.f,0.f,0.f,0.f};
        const float4* src = (const float4*)(query + ((size_t)b * LQ + (size_t)qc * QPC) * HD);
        for (int q = 0; q < QPC; q += 4) {
            float4 v0 = src[(size_t)(q + 0) * (HD / 4) + t];
            float4 v1 = src[(size_t)(q + 1) * (HD / 4) + t];
            float4 v2 = src[(size_t)(q + 2) * (HD / 4) + t];
            float4 v3 = src[(size_t)(q + 3) * (HD / 4) + t];
            a0.x += v0.x; a0.y += v0.y; a0.z += v0.z; a0.w += v0.w;
            a1.x += v1.x; a1.y += v1.y; a1.z += v1.z; a1.w += v1.w;
            a2.x += v2.x; a2.y += v2.y; a2.z += v2.z; a2.w += v2.w;
            a3.x += v3.x; a3.y += v3.y; a3.z += v3.z; a3.w += v3.w;
        }
        float4 acc = {(a0.x + a1.x) + (a2.x + a3.x), (a0.y + a1.y) + (a2.y + a3.y),
                      (a0.z + a1.z) + (a2.z + a3.z), (a0.w + a1.w) + (a2.w + a3.w)};
        ((float4*)(partial + ((size_t)qc * NB + b) * HD))[t] = acc;
    } else if (bid < NB * QCH + 16) {
        int w = t >> 6, lane = t & 63;
        int gw = (bid - NB * QCH) * 4 + w;           // 0..63
        const float4* vv = (const float4*)Wv;
        for (int r = 0; r < 16; ++r) {
            int h = gw * 16 + r;
            const float4* wr = (const float4*)(Wk + (size_t)h * AD);
            double acc = 0.0;
            #pragma unroll
            for (int j = 0; j < 2; ++j) {
                int f = lane + 64 * j;               // covers AD/4 = 128
                float4 w4 = wr[f];
                float4 v4 = vv[f];
                acc += (double)w4.x * v4.x + (double)w4.y * v4.y
                     + (double)w4.z * v4.z + (double)w4.w * v4.w;
            }
            #pragma unroll
            for (int off = 32; off > 0; off >>= 1) acc += __shfl_down(acc, off);
            if (lane == 0) wv_eff[h] = (float)acc;
        }
    } else if (t < 64) {
        int lane = t;
        const float4* br = (const float4*)bk;
        const float4* vv = (const float4*)Wv;
        double acc = 0.0;
        #pragma unroll
        for (int j = 0; j < 2; ++j) {
            int f = lane + 64 * j;
            float4 b4 = br[f];
            float4 v4 = vv[f];
            acc += (double)b4.x * v4.x + (double)b4.y * v4.y
                 + (double)b4.z * v4.z + (double)b4.w * v4.w;
        }
        #pragma unroll
        for (int off = 32; off > 0; off >>= 1) acc += __shfl_down(acc, off);
        if (lane == 0) c_v[0] = (float)(acc + (double)bv[0]);
    }
}

// =====================================================================
// K2 (kB): 256 blocks: b = bid>>3, a-chunk of 64 = (bid&7)*64.
//   Phase A: s_q[b][:] into LDS (sum of QCH partial chunks).
//   Phase B: qsum[b][a0..a0+63] = s_q·Wq[:,a] + LQ*bq[a].
// (proven round-3 pattern)
// =====================================================================
__global__ void __launch_bounds__(256)
k2_qsum(const float* __restrict__ partial, const float* __restrict__ Wq,
        const float* __restrict__ bq, float* __restrict__ qsum) {
    __shared__ float sq[HD];
    __shared__ double red[4][64];
    int b = blockIdx.x >> 3;
    int a0 = (blockIdx.x & 7) * 64;
    int t = threadIdx.x;

    #pragma unroll
    for (int c = 0; c < 4; ++c) {
        int h = t + c * 256;
        float acc = 0.f;
        #pragma unroll 4
        for (int qc = 0; qc < QCH; ++qc)
            acc += partial[((size_t)qc * NB + b) * HD + h];
        sq[h] = acc;
    }
    __syncthreads();

    int w = t >> 6, lane = t & 63;
    int a = a0 + lane;
    const float* wp = Wq + a;
    double c0 = 0.0, c1 = 0.0, c2 = 0.0, c3 = 0.0;
    int hbase = w * 256;
    for (int i = 0; i < 256; i += 4) {
        int h = hbase + i;
        c0 += (double)sq[h]     * wp[(size_t)h * AD];
        c1 += (double)sq[h + 1] * wp[(size_t)(h + 1) * AD];
        c2 += (double)sq[h + 2] * wp[(size_t)(h + 2) * AD];
        c3 += (double)sq[h + 3] * wp[(size_t)(h + 3) * AD];
    }
    red[w][lane] = ((c0 + c1) + (c2 + c3));
    __syncthreads();
    if (t < 64) {
        double s = red[0][t] + red[1][t] + red[2][t] + red[3][t];
        qsum[(size_t)b * AD + a0 + t] = (float)(s + (double)LQ * bq[a0 + t]);
    }
}

// =====================================================================
// K3 (k4_weff): 2048 blocks x 4 waves, 4 rows per wave (2 in flight):
//   wk_eff[b][h] = qsum[b]·Wk[h,:]
// =====================================================================
__global__ void __launch_bounds__(256)
k3_weff(const float* __restrict__ qsum, const float* __restrict__ Wk,
        float* __restrict__ wk_eff) {
    int w = threadIdx.x >> 6, lane = threadIdx.x & 63;
    int widx = blockIdx.x * 4 + w;                   // 8192 waves
    int base = widx * 4;                             // 4 rows each
    for (int r = 0; r < 4; r += 2) {
        int idx0 = base + r;                         // 0..32767
        int b = idx0 >> 10, h0 = idx0 & (HD - 1);
        const float4* r0 = (const float4*)(Wk + (size_t)h0 * AD);
        const float4* r1 = (const float4*)(Wk + (size_t)(h0 + 1) * AD);
        const float4* qs = (const float4*)(qsum + (size_t)b * AD);
        double a0 = 0.0, a1 = 0.0;
        #pragma unroll
        for (int j = 0; j < 2; ++j) {
            int f = lane + 64 * j;
            float4 w0 = r0[f];
            float4 w1 = r1[f];
            float4 q4 = qs[f];
            a0 += (double)w0.x * q4.x + (double)w0.y * q4.y
                + (double)w0.z * q4.z + (double)w0.w * q4.w;
            a1 += (double)w1.x * q4.x + (double)w1.y * q4.y
                + (double)w1.z * q4.z + (double)w1.w * q4.w;
        }
        #pragma unroll
        for (int off = 32; off > 0; off >>= 1) {
            a0 += __shfl_down(a0, off);
            a1 += __shfl_down(a1, off);
        }
        if (lane == 0) {
            wk_eff[idx0]     = (float)a0;
            wk_eff[idx0 + 1] = (float)a1;
        }
    }
}

// =====================================================================
// K4 (k5_scores): 2048 blocks, 32 keys each, 4 rows in flight:
//   scores = key·wk_eff[b], vvals = key·wv_eff + c_v
// =====================================================================
__global__ void __launch_bounds__(256)
k4_scores(const float* __restrict__ key, const float* __restrict__ wk_eff,
          const float* __restrict__ wv_eff, const float* __restrict__ c_v,
          float* __restrict__ scores, float* __restrict__ vvals) {
    __shared__ float lwk[HD];
    __shared__ float lwv[HD];
    const int bid = blockIdx.x;
    const int b = bid >> 6;              // 64 blocks per batch
    const int k0 = (bid & 63) * 32;
    const int t = threadIdx.x;
    for (int i = t; i < HD; i += 256) {
        lwk[i] = wk_eff[(size_t)b * HD + i];
        lwv[i] = wv_eff[i];
    }
    __syncthreads();
    int w = t >> 6, lane = t & 63;
    double cv = (double)c_v[0];
    const float4* lwk4 = (const float4*)lwk;
    const float4* lwv4 = (const float4*)lwv;
    for (int rp = 0; rp < 2; ++rp) {
        int k = k0 + w * 8 + rp * 4;
        const float4* kr0 = (const float4*)(key + ((size_t)b * LK + k) * HD);
        const float4* kr1 = kr0 + (HD / 4);
        const float4* kr2 = kr0 + 2 * (HD / 4);
        const float4* kr3 = kr0 + 3 * (HD / 4);
        double sc0 = 0.0, vv0 = 0.0, sc1 = 0.0, vv1 = 0.0;
        double sc2 = 0.0, vv2 = 0.0, sc3 = 0.0, vv3 = 0.0;
        #pragma unroll
        for (int j = 0; j < 4; ++j) {
            int f = lane + 64 * j;
            float4 k0v = kr0[f];
            float4 k1v = kr1[f];
            float4 k2v = kr2[f];
            float4 k3v = kr3[f];
            float4 wk4 = lwk4[f];
            float4 wv4 = lwv4[f];
            sc0 += (double)k0v.x * wk4.x + (double)k0v.y * wk4.y
                 + (double)k0v.z * wk4.z + (double)k0v.w * wk4.w;
            vv0 += (double)k0v.x * wv4.x + (double)k0v.y * wv4.y
                 + (double)k0v.z * wv4.z + (double)k0v.w * wv4.w;
            sc1 += (double)k1v.x * wk4.x + (double)k1v.y * wk4.y
                 + (double)k1v.z * wk4.z + (double)k1v.w * wk4.w;
            vv1 += (double)k1v.x * wv4.x + (double)k1v.y * wv4.y
                 + (double)k1v.z * wv4.z + (double)k1v.w * wv4.w;
            sc2 += (double)k2v.x * wk4.x + (double)k2v.y * wk4.y
                 + (double)k2v.z * wk4.z + (double)k2v.w * wk4.w;
            vv2 += (double)k2v.x * wv4.x + (double)k2v.y * wv4.y
                 + (double)k2v.z * wv4.z + (double)k2v.w * wv4.w;
            sc3 += (double)k3v.x * wk4.x + (double)k3v.y * wk4.y
                 + (double)k3v.z * wk4.z + (double)k3v.w * wk4.w;
            vv3 += (double)k3v.x * wv4.x + (double)k3v.y * wv4.y
                 + (double)k3v.z * wv4.z + (double)k3v.w * wv4.w;
        }
        #pragma unroll
        for (int off = 32; off > 0; off >>= 1) {
            sc0 += __shfl_down(sc0, off);
            vv0 += __shfl_down(vv0, off);
            sc1 += __shfl_down(sc1, off);
            vv1 += __shfl_down(vv1, off);
            sc2 += __shfl_down(sc2, off);
            vv2 += __shfl_down(vv2, off);
            sc3 += __shfl_down(sc3, off);
            vv3 += __shfl_down(vv3, off);
        }
        if (lane == 0) {
            size_t base = (size_t)b * LK + k;
            scores[base]     = (float)sc0;  vvals[base]     = (float)(vv0 + cv);
            scores[base + 1] = (float)sc1;  vvals[base + 1] = (float)(vv1 + cv);
            scores[base + 2] = (float)sc2;  vvals[base + 2] = (float)(vv2 + cv);
            scores[base + 3] = (float)sc3;  vvals[base + 3] = (float)(vv3 + cv);
        }
    }
}

// =====================================================================
// K5 (k6_softmax): per-batch softmax + weighted sum -> out[b]
// =====================================================================
__global__ void __launch_bounds__(256)
k5_softmax(const float* __restrict__ scores, const float* __restrict__ vvals,
           float* __restrict__ out) {
    int b = blockIdx.x;
    int t = threadIdx.x;
    __shared__ float smax_sh[4];
    __shared__ double num_sh[4], den_sh[4];
    const float* sr = scores + (size_t)b * LK;
    const float* vr = vvals  + (size_t)b * LK;
    float m = -INFINITY;
    for (int k = t; k < LK; k += 256) m = fmaxf(m, sr[k]);
    #pragma unroll
    for (int off = 32; off > 0; off >>= 1) m = fmaxf(m, __shfl_down(m, off));
    int w = t >> 6, lane = t & 63;
    if (lane == 0) smax_sh[w] = m;
    __syncthreads();
    float gm = fmaxf(fmaxf(smax_sh[0], smax_sh[1]), fmaxf(smax_sh[2], smax_sh[3]));
    double num = 0.0, den = 0.0;
    for (int k = t; k < LK; k += 256) {
        double e = exp((double)(sr[k] - gm));
        den += e;
        num += e * (double)vr[k];
    }
    #pragma unroll
    for (int off = 32; off > 0; off >>= 1) {
        num += __shfl_down(num, off);
        den += __shfl_down(den, off);
    }
    if (lane == 0) { num_sh[w] = num; den_sh[w] = den; }
    __syncthreads();
    if (t == 0) {
        double N = num_sh[0] + num_sh[1] + num_sh[2] + num_sh[3];
        double D = den_sh[0] + den_sh[1] + den_sh[2] + den_sh[3];
        out[b] = (float)(N / D);
    }
}

extern "C" void kernel_launch(void* const* d_in, const int* in_sizes, int n_in,
                              void* d_out, int out_size, void* d_ws, size_t ws_size,
                              hipStream_t stream) {
    const float* query = (const float*)d_in[0];
    const float* key   = (const float*)d_in[1];
    const float* Wq    = (const float*)d_in[2];
    const float* bq    = (const float*)d_in[3];
    const float* Wk    = (const float*)d_in[4];
    const float* bk    = (const float*)d_in[5];
    const float* Wv    = (const float*)d_in[6];
    const float* bv    = (const float*)d_in[7];
    float* out = (float*)d_out;

    float* ws = (float*)d_ws;
    size_t off = 0;
    float* partial = ws + off; off += (size_t)QCH * NB * HD;   // 4 MB
    float* qsum    = ws + off; off += (size_t)NB * AD;
    float* wk_eff  = ws + off; off += (size_t)NB * HD;
    float* wv_eff  = ws + off; off += (size_t)HD;
    float* c_v     = ws + off; off += 1;
    float* scores  = ws + off; off += (size_t)NB * LK;
    float* vvals   = ws + off; off += (size_t)NB * LK;

    hipLaunchKernelGGL(k1_stream, dim3(NB * QCH + 16 + 1), dim3(256), 0, stream,
                       query, Wk, Wv, bk, bv, partial, wv_eff, c_v);
    hipLaunchKernelGGL(k2_qsum, dim3(256), dim3(256), 0, stream,
                       partial, Wq, bq, qsum);
    hipLaunchKernelGGL(k3_weff, dim3(2048), dim3(256), 0, stream,
                       qsum, Wk, wk_eff);
    hipLaunchKernelGGL(k4_scores, dim3(NB * (LK / 32)), dim3(256), 0, stream,
                       key, wk_eff, wv_eff, c_v, scores, vvals);
    hipLaunchKernelGGL(k5_softmax, dim3(NB), dim3(256), 0, stream,
                       scores, vvals, out);
}